// Round 14
// baseline (1819.812 us; speedup 1.0000x reference)
//
#include <hip/hip_runtime.h>
#include <hip/hip_fp16.h>
#include <stdint.h>

// ---------- types ----------
typedef _Float16 half8 __attribute__((ext_vector_type(8)));
typedef _Float16 h2v __attribute__((ext_vector_type(2)));
typedef float f32x4 __attribute__((ext_vector_type(4)));

#define GLD_LDS16(gp, lp)                                                     \
  __builtin_amdgcn_global_load_lds(                                           \
      (const __attribute__((address_space(1))) void*)(gp),                    \
      (__attribute__((address_space(3))) void*)(lp), 16, 0, 0)
#define GLD_LDS4(gp, lp)                                                      \
  __builtin_amdgcn_global_load_lds(                                           \
      (const __attribute__((address_space(1))) void*)(gp),                    \
      (__attribute__((address_space(3))) void*)(lp), 4, 0, 0)

#define SBAR() asm volatile("s_barrier" ::: "memory")

// ---------- x convert: fp32 (harness upcast) -> fp16 ----------
__global__ void xcvt_kernel(const float* __restrict__ in, __half* __restrict__ out) {
  const size_t i = ((size_t)blockIdx.x * 256 + threadIdx.x) * 4;
  float4 v = *(const float4*)(in + i);
  __half2* o = (__half2*)(out + i);
  o[0] = __floats2half2_rn(v.x, v.y);
  o[1] = __floats2half2_rn(v.z, v.w);
}

// ---------- repack: qweight [K][N/8] col-packed -> [K/8][N] k-packed ----------
// Output dword for (q, n): nibble of k=8q+t placed at bits 4*(t>>1) + 16*(t&1),
// so that (p >> 4j) & 0x000F000F gives halves (k=2j, k=2j+1).
__global__ void repack_kernel(const int* __restrict__ qw, uint32_t* __restrict__ rp, int P) {
  const int N = P * 8;
  const int n = blockIdx.x * 256 + threadIdx.x;
  const int j8 = n >> 3;
  const int sh = (n & 7) * 4;
  #pragma unroll
  for (int qi = 0; qi < 4; ++qi) {
    const int q = blockIdx.y * 4 + qi;
    const int* src = qw + (size_t)(q * 8) * P + j8;
    uint32_t r = 0;
    #pragma unroll
    for (int t = 0; t < 8; ++t) {
      uint32_t w = ((uint32_t)src[t * P] >> sh) & 15u;
      r |= w << (4 * (t >> 1) + 16 * (t & 1));
    }
    rp[(size_t)q * N + n] = r;
  }
}

// ---------- smz: per (group, col) pack (s_bits, (1024+z)_bits) ----------
__global__ void smz_kernel(const float* __restrict__ sc, const int* __restrict__ qz,
                           uint32_t* __restrict__ smz, int P) {
  const int N = P * 8;
  const int n = blockIdx.x * 256 + threadIdx.x;
  const int g = blockIdx.y;
  uint32_t sbits = __half_as_ushort(__float2half(sc[(size_t)g * N + n]));  // exact
  uint32_t z = ((uint32_t)qz[(size_t)g * P + (n >> 3)] >> ((n & 7) * 4)) & 15u;
  uint32_t hz = 0x6400u | z;  // fp16(1024+z), exact
  smz[(size_t)g * N + n] = sbits | (hz << 16);
}

// ---------- dequant 8 nibbles -> half8 (pk-f16 ops) ----------
union U32H2 { uint32_t u; h2v h; };
__device__ inline h2v bith2(uint32_t u) { U32H2 t; t.u = u; return t.h; }
__device__ inline uint32_t h2bit(h2v h) { U32H2 t; t.h = h; return t.u; }
__device__ inline half8 dequant8(uint32_t p, h2v s, h2v z) {
  union { uint32_t u[4]; half8 v; } r;
  r.u[0] = h2bit((bith2((p & 0x000F000Fu) | 0x64006400u) - z) * s);
  r.u[1] = h2bit((bith2(((p >> 4) & 0x000F000Fu) | 0x64006400u) - z) * s);
  r.u[2] = h2bit((bith2(((p >> 8) & 0x000F000Fu) | 0x64006400u) - z) * s);
  r.u[3] = h2bit((bith2(((p >> 12) & 0x000F000Fu) | 0x64006400u) - z) * s);
  return r.v;  // v_pk_sub_f16 (exact) + v_pk_mul_f16 (1 rounding) per dword
}

// ---------- fused AWQ GEMM — m201-style 8-phase / 256x256 tile ----------
// Block: 512 threads = 8 waves (2M x 4N). 256 rows x 256 cols
// (cols = 128 at n0 ["gate"] + 128 at n0+T1OFF ["up"]; GEMM2: T1OFF=128 ->
// contiguous 256). Wave (wm = wv>>2, wn = wv&3) owns rows wm*128..+127 and
// cols wn*32..+31 of both halves -> acc[4 nf][8 mf] f32x4 = 128 VGPR;
// dequant 4 per kk feeding 32 MFMAs (1:8 ratio preserved).
// K-tile (BK=64) split into 4 PHASES (kk x mf-half), each:
//   {ds_read 4xb128 A (+4xb32 B +smz-unpack on kk-entry) ; issue 1-2 staging
//    loads ; s_barrier ; setprio(1) ; dequant+16 MFMA ; setprio(0) ; s_barrier}
// This fine interleave de-convoys the waves: at any instant some waves are in
// ds_read/VALU and others in MFMA (T3); counted vmcnt once per K-tile (T4):
// batch(k) = 4xA + 1xB (+1 smz if k even) -> wait vmcnt(6/5) by parity,
// vmcnt(0) only for the last two tiles. Raw s_barrier (memory-clobber asm),
// never __syncthreads, so the staging queue is never drained mid-loop.
// A: row-major XOR-swizzled (slot c at row m holds chunk c^(m&7)) — proven 0
// bank conflicts. B: R13 layout, dword (qr,c) holds RP col map(c^S(qr)),
// S(qr)=((qr&1)<<4)|((qr>>1)<<2). LDS total 124928 B -> 1 block/CU.
template <int KDIM, int NW, int T1OFF, int OW, bool SILU, int BXS>
__global__ __launch_bounds__(512, 2) void awq_gemm(const __half* __restrict__ A,
                                                   const uint32_t* __restrict__ RP,
                                                   const uint32_t* __restrict__ SMZ,
                                                   void* __restrict__ OUT) {
  constexpr int ABUF = 256 * 64 * 2;          // 32768 B per A buffer
  constexpr int BBUF = 8 * 256 * 4;           // 8192 B per B buffer
  constexpr int BOFF = 3 * ABUF;              // 98304
  constexpr int ZOFF = BOFF + 3 * BBUF;       // 122880; smz dbuf 2 x 1024
  __shared__ __align__(16) unsigned char smem[ZOFF + 2048];  // 124928

  const int tid = threadIdx.x;
  const int l = tid & 63;
  const int wv = tid >> 6;      // 0..7
  const int wm = wv >> 2;       // row half (128 rows)
  const int wn = wv & 3;        // col quarter (32 cols per 128-half)
  const int l15 = l & 15;
  const int l4 = l >> 4;
  const int l157 = l15 & 7;

  const int row0 = blockIdx.y * 256;
  const int n0 = blockIdx.x * BXS;

  // A staging sources (4 iters x 512 thr x 16B = 32KB):
  // iter it: m = it*64 + tid>>3, slot cs = tid&7 holds chunk cs^(m&7)
  const __half* asrc[4];
  #pragma unroll
  for (int it = 0; it < 4; ++it) {
    int m = it * 64 + (tid >> 3);
    int cs = tid & 7;
    int kc = cs ^ (m & 7);
    asrc[it] = A + (size_t)(row0 + m) * KDIM + kc * 8;
  }

  // B staging source (1 x 512 thr x 16B = 8KB):
  // dword (qr = tid>>6, c = (tid&63)*4..+3) holds RP col map(c ^ S(qr))
  const uint32_t* bsrc;
  {
    int qr = tid >> 6;
    int c4 = (tid & 63) * 4;
    int S = ((qr & 1) << 4) | ((qr >> 1) << 2);
    int cS = c4 ^ S;                       // S bits 2,4: 4-dword run stays contiguous
    int bcol = (cS < 128) ? n0 + cS : n0 + T1OFF + (cS - 128);
    bsrc = RP + (size_t)qr * NW + bcol;
  }

  // SMZ staging source: zc = tid&255 covers 256 LDS dwords (upper waves duplicate)
  const uint32_t* zsrc;
  {
    int zc = tid & 255;
    zsrc = SMZ + ((zc < 128) ? n0 + zc : n0 + T1OFF + (zc - 128));
  }

  // lane-constant column indices (LDS col space 0..255) and A row offsets
  int chi[4];
  #pragma unroll
  for (int nf = 0; nf < 4; ++nf)
    chi[nf] = (nf >> 1) * 128 + wn * 32 + (nf & 1) * 16 + l15;
  int arow[8];
  #pragma unroll
  for (int mf = 0; mf < 8; ++mf)
    arow[mf] = (wm * 128 + mf * 16 + l15) * 128;

  f32x4 acc[4][8];
  const f32x4 zero4 = {0.f, 0.f, 0.f, 0.f};
  #pragma unroll
  for (int nf = 0; nf < 4; ++nf)
    #pragma unroll
    for (int mf = 0; mf < 8; ++mf) acc[nf][mf] = zero4;

  uint32_t s2[4], z2[4];
  constexpr int NSTEP = KDIM / 64;

  // ---- prologue: batch(0) [4A,B,smz g0] then batch(1) [4A,B] ----
  #pragma unroll
  for (int it = 0; it < 4; ++it)
    GLD_LDS16(asrc[it], &smem[it * 8192 + tid * 16]);
  GLD_LDS16(bsrc, &smem[BOFF + tid * 16]);
  GLD_LDS4(zsrc, &smem[ZOFF + (tid & 255) * 4]);
  #pragma unroll
  for (int it = 0; it < 4; ++it)
    GLD_LDS16(asrc[it] + 64, &smem[ABUF + it * 8192 + tid * 16]);
  GLD_LDS16(bsrc + (size_t)8 * NW, &smem[BOFF + BBUF + tid * 16]);

  asm volatile("s_waitcnt vmcnt(5)" ::: "memory");  // batch(0) landed
  SBAR();

  int cur = 0, stg = 2;
  for (int t = 0; t < NSTEP; ++t) {
    const int aoff = cur * ABUF;
    uint32_t bq[4];
    half8 afr[4], bfr[4];
    const uint32_t* bdw = (const uint32_t*)&smem[BOFF + cur * BBUF];
    const int Sl0 = ((l4 & 1) << 4) | ((l4 >> 1) << 2);

    // ===== PHASE 0: kk=0, mf 0-3 (B read + dequant) =====
    if (t + 2 < NSTEP) {
      GLD_LDS16(asrc[0] + (size_t)(t + 2) * 64, &smem[stg * ABUF + tid * 16]);
      GLD_LDS16(asrc[1] + (size_t)(t + 2) * 64, &smem[stg * ABUF + 8192 + tid * 16]);
    }
    #pragma unroll
    for (int nf = 0; nf < 4; ++nf)
      bq[nf] = bdw[l4 * 256 + (chi[nf] ^ Sl0)];
    if ((t & 1) == 0) {  // group boundary: unpack s/z from zbuf ((t>>1)&1)
      const uint32_t* zl = (const uint32_t*)&smem[ZOFF + ((t >> 1) & 1) * 1024];
      #pragma unroll
      for (int nf = 0; nf < 4; ++nf) {
        uint32_t u = zl[chi[nf]];
        uint32_t lo = u & 0xFFFFu;
        s2[nf] = lo | (lo << 16);
        z2[nf] = (u & 0xFFFF0000u) | (u >> 16);
      }
    }
    #pragma unroll
    for (int i = 0; i < 4; ++i)
      afr[i] = *(const half8*)&smem[aoff + arow[i] + (l4 ^ l157) * 16];
    SBAR();
    __builtin_amdgcn_s_setprio(1);
    #pragma unroll
    for (int nf = 0; nf < 4; ++nf)
      bfr[nf] = dequant8(bq[nf], bith2(s2[nf]), bith2(z2[nf]));
    #pragma unroll
    for (int nf = 0; nf < 4; ++nf)
      #pragma unroll
      for (int i = 0; i < 4; ++i)
        acc[nf][i] = __builtin_amdgcn_mfma_f32_16x16x32_f16(afr[i], bfr[nf], acc[nf][i], 0, 0, 0);
    __builtin_amdgcn_s_setprio(0);
    SBAR();

    // ===== PHASE 1: kk=0, mf 4-7 (reuse bfr) =====
    if (t + 2 < NSTEP) {
      GLD_LDS16(asrc[2] + (size_t)(t + 2) * 64, &smem[stg * ABUF + 16384 + tid * 16]);
      GLD_LDS16(asrc[3] + (size_t)(t + 2) * 64, &smem[stg * ABUF + 24576 + tid * 16]);
    }
    #pragma unroll
    for (int i = 0; i < 4; ++i)
      afr[i] = *(const half8*)&smem[aoff + arow[4 + i] + (l4 ^ l157) * 16];
    SBAR();
    __builtin_amdgcn_s_setprio(1);
    #pragma unroll
    for (int nf = 0; nf < 4; ++nf)
      #pragma unroll
      for (int i = 0; i < 4; ++i)
        acc[nf][4 + i] = __builtin_amdgcn_mfma_f32_16x16x32_f16(afr[i], bfr[nf], acc[nf][4 + i], 0, 0, 0);
    __builtin_amdgcn_s_setprio(0);
    SBAR();

    // ===== PHASE 2: kk=1, mf 0-3 (B read + dequant) =====
    if (t + 2 < NSTEP) {
      GLD_LDS16(bsrc + (size_t)(t + 2) * 8 * NW, &smem[BOFF + stg * BBUF + tid * 16]);
      if (((t + 2) & 1) == 0) {
        const int g = (t + 2) >> 1;
        GLD_LDS4(zsrc + (size_t)g * NW, &smem[ZOFF + (g & 1) * 1024 + (tid & 255) * 4]);
      }
    }
    #pragma unroll
    for (int nf = 0; nf < 4; ++nf)
      bq[nf] = bdw[(4 + l4) * 256 + (chi[nf] ^ (Sl0 | 8))];
    #pragma unroll
    for (int i = 0; i < 4; ++i)
      afr[i] = *(const half8*)&smem[aoff + arow[i] + ((4 + l4) ^ l157) * 16];
    SBAR();
    __builtin_amdgcn_s_setprio(1);
    #pragma unroll
    for (int nf = 0; nf < 4; ++nf)
      bfr[nf] = dequant8(bq[nf], bith2(s2[nf]), bith2(z2[nf]));
    #pragma unroll
    for (int nf = 0; nf < 4; ++nf)
      #pragma unroll
      for (int i = 0; i < 4; ++i)
        acc[nf][i] = __builtin_amdgcn_mfma_f32_16x16x32_f16(afr[i], bfr[nf], acc[nf][i], 0, 0, 0);
    __builtin_amdgcn_s_setprio(0);
    SBAR();

    // ===== PHASE 3: kk=1, mf 4-7 (reuse bfr) + tile-boundary counted wait =====
    #pragma unroll
    for (int i = 0; i < 4; ++i)
      afr[i] = *(const half8*)&smem[aoff + arow[4 + i] + ((4 + l4) ^ l157) * 16];
    SBAR();
    __builtin_amdgcn_s_setprio(1);
    #pragma unroll
    for (int nf = 0; nf < 4; ++nf)
      #pragma unroll
      for (int i = 0; i < 4; ++i)
        acc[nf][4 + i] = __builtin_amdgcn_mfma_f32_16x16x32_f16(afr[i], bfr[nf], acc[nf][4 + i], 0, 0, 0);
    __builtin_amdgcn_s_setprio(0);
    // counted wait: ensure batch(t+1) landed; leave batch(t+2) in flight
    if (t + 2 >= NSTEP)      asm volatile("s_waitcnt vmcnt(0)" ::: "memory");
    else if (t & 1)          asm volatile("s_waitcnt vmcnt(5)" ::: "memory");
    else                     asm volatile("s_waitcnt vmcnt(6)" ::: "memory");
    SBAR();

    cur = (cur == 2) ? 0 : cur + 1;
    stg = (stg == 2) ? 0 : stg + 1;
  }

  // epilogue: C/D: col = l15, row = mf*16 + l4*4 + r
  if (SILU) {
    __half* O = (__half*)OUT;
    #pragma unroll
    for (int nfg = 0; nfg < 2; ++nfg)
      #pragma unroll
      for (int mf = 0; mf < 8; ++mf)
        #pragma unroll
        for (int r = 0; r < 4; ++r) {
          int row = row0 + wm * 128 + mf * 16 + l4 * 4 + r;
          int col = n0 + wn * 32 + nfg * 16 + l15;
          float gf = __half2float(__float2half(acc[nfg][mf][r]));      // gate fp16 cast
          float uf = __half2float(__float2half(acc[2 + nfg][mf][r]));  // up fp16 cast
          float sig = 1.f / (1.f + __expf(-gf));
          float sil = __half2float(__float2half(gf * sig));            // silu fp16 cast
          O[(size_t)row * OW + col] = __float2half(sil * uf);          // intermediate fp16
        }
  } else {
    float* O = (float*)OUT;
    #pragma unroll
    for (int nf = 0; nf < 4; ++nf)
      #pragma unroll
      for (int mf = 0; mf < 8; ++mf)
        #pragma unroll
        for (int r = 0; r < 4; ++r) {
          int row = row0 + wm * 128 + mf * 16 + l4 * 4 + r;
          int col = n0 + (nf >> 1) * T1OFF + wn * 32 + (nf & 1) * 16 + l15;
          O[(size_t)row * OW + col] = __half2float(__float2half(acc[nf][mf][r]));
        }
  }
}

// ---------- launch ----------
// Workspace phase-aliasing (stay under round-1-proven-safe 263,397,376 B):
//   phase 1 (through GEMM1): interm | rp_gu | smz_gu | xh   = 256,688,128 B
//   phase 2 (after GEMM1):   interm | rp_dn | smz_dn        = 191,258,624 B
extern "C" void kernel_launch(void* const* d_in, const int* in_sizes, int n_in,
                              void* d_out, int out_size, void* d_ws, size_t ws_size,
                              hipStream_t stream) {
  const float* x_f32 = (const float*)d_in[0];          // harness upcasts fp16 -> fp32
  const int* qw_gu = (const int*)d_in[1];
  const int* qz_gu = (const int*)d_in[2];
  const float* sc_gu = (const float*)d_in[3];          // fp32 (upcast)
  const int* qw_dn = (const int*)d_in[4];
  const int* qz_dn = (const int*)d_in[5];
  const float* sc_dn = (const float*)d_in[6];          // fp32 (upcast)

  char* ws = (char*)d_ws;
  __half* interm   = (__half*)ws;                      // 155,189,248
  uint32_t* rp_gu  = (uint32_t*)(ws + 155189248ull);   // 67,895,296
  uint32_t* smz_gu = (uint32_t*)(ws + 223084544ull);   // 4,243,456
  __half* xh       = (__half*)(ws + 227328000ull);     // 29,360,128
  uint32_t* rp_dn  = (uint32_t*)(ws + 155189248ull);   // aliases rp_gu
  uint32_t* smz_dn = (uint32_t*)(ws + 189136896ull);

  // ---- phase 1: prep + GEMM1 ----
  xcvt_kernel<<<14336, 256, 0, stream>>>(x_f32, xh);
  repack_kernel<<<dim3(148, 112), 256, 0, stream>>>(qw_gu, rp_gu, 4736);
  smz_kernel<<<dim3(148, 28), 256, 0, stream>>>(sc_gu, qz_gu, smz_gu, 4736);

  // GEMM1: block = 256 rows x (128 gate cols at n0 + 128 up cols at n0+18944)
  awq_gemm<3584, 37888, 18944, 18944, true, 128>
      <<<dim3(148, 16), 512, 0, stream>>>(xh, rp_gu, smz_gu, (void*)interm);

  // ---- phase 2: prep + GEMM2 (aliased scratch) ----
  repack_kernel<<<dim3(14, 592), 256, 0, stream>>>(qw_dn, rp_dn, 448);
  smz_kernel<<<dim3(14, 148), 256, 0, stream>>>(sc_dn, qz_dn, smz_dn, 448);

  // GEMM2: block = 256 rows x 256 contiguous cols (T1OFF=128)
  awq_gemm<18944, 3584, 128, 3584, false, 256>
      <<<dim3(14, 16), 512, 0, stream>>>(interm, rp_dn, smz_dn, d_out);
}

// Round 15
// 1683.243 us; speedup vs baseline: 1.0811x; 1.0811x over previous
//
#include <hip/hip_runtime.h>
#include <hip/hip_fp16.h>
#include <stdint.h>

// ---------- types ----------
typedef _Float16 half8 __attribute__((ext_vector_type(8)));
typedef _Float16 h2v __attribute__((ext_vector_type(2)));
typedef float f32x4 __attribute__((ext_vector_type(4)));

#define GLD_LDS16(gp, lp)                                                     \
  __builtin_amdgcn_global_load_lds(                                           \
      (const __attribute__((address_space(1))) void*)(gp),                    \
      (__attribute__((address_space(3))) void*)(lp), 16, 0, 0)
#define GLD_LDS4(gp, lp)                                                      \
  __builtin_amdgcn_global_load_lds(                                           \
      (const __attribute__((address_space(1))) void*)(gp),                    \
      (__attribute__((address_space(3))) void*)(lp), 4, 0, 0)

// ---------- x convert: fp32 (harness upcast) -> fp16 ----------
__global__ void xcvt_kernel(const float* __restrict__ in, __half* __restrict__ out) {
  const size_t i = ((size_t)blockIdx.x * 256 + threadIdx.x) * 4;
  float4 v = *(const float4*)(in + i);
  __half2* o = (__half2*)(out + i);
  o[0] = __floats2half2_rn(v.x, v.y);
  o[1] = __floats2half2_rn(v.z, v.w);
}

// ---------- repack: qweight [K][N/8] col-packed -> [K/8][N] k-packed ----------
__global__ void repack_kernel(const int* __restrict__ qw, uint32_t* __restrict__ rp, int P) {
  const int N = P * 8;
  const int n = blockIdx.x * 256 + threadIdx.x;
  const int j8 = n >> 3;
  const int sh = (n & 7) * 4;
  #pragma unroll
  for (int qi = 0; qi < 4; ++qi) {
    const int q = blockIdx.y * 4 + qi;
    const int* src = qw + (size_t)(q * 8) * P + j8;
    uint32_t r = 0;
    #pragma unroll
    for (int t = 0; t < 8; ++t) {
      uint32_t w = ((uint32_t)src[t * P] >> sh) & 15u;
      r |= w << (4 * (t >> 1) + 16 * (t & 1));
    }
    rp[(size_t)q * N + n] = r;
  }
}

// ---------- smz: per (group, col) pack (s_bits, (1024+z)_bits) ----------
__global__ void smz_kernel(const float* __restrict__ sc, const int* __restrict__ qz,
                           uint32_t* __restrict__ smz, int P) {
  const int N = P * 8;
  const int n = blockIdx.x * 256 + threadIdx.x;
  const int g = blockIdx.y;
  uint32_t sbits = __half_as_ushort(__float2half(sc[(size_t)g * N + n]));  // exact
  uint32_t z = ((uint32_t)qz[(size_t)g * P + (n >> 3)] >> ((n & 7) * 4)) & 15u;
  uint32_t hz = 0x6400u | z;  // fp16(1024+z), exact
  smz[(size_t)g * N + n] = sbits | (hz << 16);
}

// ---------- dequant 8 nibbles -> half8 (pk-f16 ops) ----------
union U32H2 { uint32_t u; h2v h; };
__device__ inline h2v bith2(uint32_t u) { U32H2 t; t.u = u; return t.h; }
__device__ inline uint32_t h2bit(h2v h) { U32H2 t; t.h = h; return t.u; }
__device__ inline half8 dequant8(uint32_t p, h2v s, h2v z) {
  union { uint32_t u[4]; half8 v; } r;
  r.u[0] = h2bit((bith2((p & 0x000F000Fu) | 0x64006400u) - z) * s);
  r.u[1] = h2bit((bith2(((p >> 4) & 0x000F000Fu) | 0x64006400u) - z) * s);
  r.u[2] = h2bit((bith2(((p >> 8) & 0x000F000Fu) | 0x64006400u) - z) * s);
  r.u[3] = h2bit((bith2(((p >> 12) & 0x000F000Fu) | 0x64006400u) - z) * s);
  return r.v;  // v_pk_sub_f16 (exact) + v_pk_mul_f16 (1 rounding) per dword
}

// ========== GEMM1 kernel: 256x256 tile, R13 single-barrier schedule ==========
// Block: 512 threads = 8 waves (2M x 4N). 256 rows x 256 cols
// (128 at n0 "gate" + 128 at n0+T1OFF "up"). Wave (wm=wv>>2, wn=wv&3) owns
// rows wm*128..+127, cols wn*32..+31 of both halves -> wave tile 128x64:
//   per K-step: 16 A b128 + 8 B b32 + 8 dequant8 + 64 MFMA (1:8 ratio),
//   LDS/MFMA = 16*12/64 + 8*5.8/64 + stage ~= 4.4 cyc < matrix 4.85 cyc
//   (vs 6.7 at wN=32) -> matrix-bound on paper for the first time.
// Layouts byte-identical to R14 (verified): A row-major XOR-swizzle
// (slot c at row m holds chunk c^(m&7)), B dword (qr,c) holds RP col
// map(c^S(qr)), S(qr)=((qr&1)<<4)|((qr>>1)<<2); smz dbuf 2x1KB.
// Schedule identical to R13 (proven): triple-buffer, ONE raw s_barrier per
// K-step preceded by COUNTED s_waitcnt vmcnt; batch(k) = 4A+1B (+1 smz if k
// even) -> wait vmcnt(5) t even / vmcnt(6) t odd / vmcnt(0) last.
// LDS 124928 B -> 1 block/CU.
template <int KDIM, int NW, int T1OFF, int OW, bool SILU, int BXS>
__global__ __launch_bounds__(512, 2) void awq_gemm_big(const __half* __restrict__ A,
                                                       const uint32_t* __restrict__ RP,
                                                       const uint32_t* __restrict__ SMZ,
                                                       void* __restrict__ OUT) {
  constexpr int ABUF = 256 * 64 * 2;          // 32768 B per A buffer
  constexpr int BBUF = 8 * 256 * 4;           // 8192 B per B buffer
  constexpr int BOFF = 3 * ABUF;              // 98304
  constexpr int ZOFF = BOFF + 3 * BBUF;       // 122880; smz dbuf 2 x 1024
  __shared__ __align__(16) unsigned char smem[ZOFF + 2048];  // 124928

  const int tid = threadIdx.x;
  const int l = tid & 63;
  const int wv = tid >> 6;
  const int wm = wv >> 2;
  const int wn = wv & 3;
  const int l15 = l & 15;
  const int l4 = l >> 4;
  const int l157 = l15 & 7;

  const int row0 = blockIdx.y * 256;
  const int n0 = blockIdx.x * BXS;

  // A staging sources (4 iters x 512 thr x 16B = 32KB)
  const __half* asrc[4];
  #pragma unroll
  for (int it = 0; it < 4; ++it) {
    int m = it * 64 + (tid >> 3);
    int cs = tid & 7;
    int kc = cs ^ (m & 7);
    asrc[it] = A + (size_t)(row0 + m) * KDIM + kc * 8;
  }

  // B staging source (512 thr x 16B = 8KB)
  const uint32_t* bsrc;
  {
    int qr = tid >> 6;
    int c4 = (tid & 63) * 4;
    int S = ((qr & 1) << 4) | ((qr >> 1) << 2);
    int cS = c4 ^ S;
    int bcol = (cS < 128) ? n0 + cS : n0 + T1OFF + (cS - 128);
    bsrc = RP + (size_t)qr * NW + bcol;
  }

  // SMZ staging source (256 dwords; upper half duplicates)
  const uint32_t* zsrc;
  {
    int zc = tid & 255;
    zsrc = SMZ + ((zc < 128) ? n0 + zc : n0 + T1OFF + (zc - 128));
  }

  int chi[4];
  #pragma unroll
  for (int nf = 0; nf < 4; ++nf)
    chi[nf] = (nf >> 1) * 128 + wn * 32 + (nf & 1) * 16 + l15;
  int arow[8];
  #pragma unroll
  for (int mf = 0; mf < 8; ++mf)
    arow[mf] = (wm * 128 + mf * 16 + l15) * 128;

  f32x4 acc[4][8];
  const f32x4 zero4 = {0.f, 0.f, 0.f, 0.f};
  #pragma unroll
  for (int nf = 0; nf < 4; ++nf)
    #pragma unroll
    for (int mf = 0; mf < 8; ++mf) acc[nf][mf] = zero4;

  uint32_t s2[4], z2[4];
  constexpr int NSTEP = KDIM / 64;

  // ---- prologue: batch(0) [4A,B,smz g0] then batch(1) [4A,B] ----
  #pragma unroll
  for (int it = 0; it < 4; ++it)
    GLD_LDS16(asrc[it], &smem[it * 8192 + tid * 16]);
  GLD_LDS16(bsrc, &smem[BOFF + tid * 16]);
  GLD_LDS4(zsrc, &smem[ZOFF + (tid & 255) * 4]);
  #pragma unroll
  for (int it = 0; it < 4; ++it)
    GLD_LDS16(asrc[it] + 64, &smem[ABUF + it * 8192 + tid * 16]);
  GLD_LDS16(bsrc + (size_t)8 * NW, &smem[BOFF + BBUF + tid * 16]);

  int cur = 0, stg = 2;
  for (int t = 0; t < NSTEP; ++t) {
    // counted wait: drain batch(t); leave batch(t+1) = 5 (t even) / 6 (t odd)
    if (t == NSTEP - 1)      asm volatile("s_waitcnt vmcnt(0)" ::: "memory");
    else if (t & 1)          asm volatile("s_waitcnt vmcnt(6)" ::: "memory");
    else                     asm volatile("s_waitcnt vmcnt(5)" ::: "memory");
    __builtin_amdgcn_s_barrier();

    // issue batch(t+2) into buf stg
    if (t + 2 < NSTEP) {
      #pragma unroll
      for (int it = 0; it < 4; ++it)
        GLD_LDS16(asrc[it] + (size_t)(t + 2) * 64,
                  &smem[stg * ABUF + it * 8192 + tid * 16]);
      GLD_LDS16(bsrc + (size_t)(t + 2) * 8 * NW, &smem[BOFF + stg * BBUF + tid * 16]);
      if (((t + 2) & 1) == 0) {
        const int g = (t + 2) >> 1;
        GLD_LDS4(zsrc + (size_t)g * NW, &smem[ZOFF + (g & 1) * 1024 + (tid & 255) * 4]);
      }
    }

    if ((t & 1) == 0) {  // group boundary: unpack s/z from zbuf ((t>>1)&1)
      const uint32_t* zl = (const uint32_t*)&smem[ZOFF + ((t >> 1) & 1) * 1024];
      #pragma unroll
      for (int nf = 0; nf < 4; ++nf) {
        uint32_t u = zl[chi[nf]];
        uint32_t lo = u & 0xFFFFu;
        s2[nf] = lo | (lo << 16);
        z2[nf] = (u & 0xFFFF0000u) | (u >> 16);
      }
    }

    // B dwords for both kk (8 b32, swizzle-matched)
    uint32_t bq[2][4];
    const uint32_t* bdw = (const uint32_t*)&smem[BOFF + cur * BBUF];
    #pragma unroll
    for (int kk = 0; kk < 2; ++kk) {
      const int Sl = ((l4 & 1) << 4) | (kk << 3) | ((l4 >> 1) << 2);
      #pragma unroll
      for (int nf = 0; nf < 4; ++nf)
        bq[kk][nf] = bdw[(kk * 4 + l4) * 256 + (chi[nf] ^ Sl)];
    }

    const unsigned char* abase = &smem[cur * ABUF];
    __builtin_amdgcn_s_setprio(1);
    #pragma unroll
    for (int kk = 0; kk < 2; ++kk) {
      const int coff = ((kk * 4 + l4) ^ l157) * 16;
      half8 afr[8];
      #pragma unroll
      for (int mf = 0; mf < 8; ++mf)
        afr[mf] = *(const half8*)&smem[(size_t)(abase - smem) + arow[mf] + coff];
      half8 bfr[4];
      #pragma unroll
      for (int nf = 0; nf < 4; ++nf)
        bfr[nf] = dequant8(bq[kk][nf], bith2(s2[nf]), bith2(z2[nf]));
      #pragma unroll
      for (int nf = 0; nf < 4; ++nf)
        #pragma unroll
        for (int mf = 0; mf < 8; ++mf)
          acc[nf][mf] =
              __builtin_amdgcn_mfma_f32_16x16x32_f16(afr[mf], bfr[nf], acc[nf][mf], 0, 0, 0);
    }
    __builtin_amdgcn_s_setprio(0);

    cur = (cur == 2) ? 0 : cur + 1;
    stg = (stg == 2) ? 0 : stg + 1;
  }

  // epilogue
  if (SILU) {
    __half* O = (__half*)OUT;
    #pragma unroll
    for (int nfg = 0; nfg < 2; ++nfg)
      #pragma unroll
      for (int mf = 0; mf < 8; ++mf)
        #pragma unroll
        for (int r = 0; r < 4; ++r) {
          int row = row0 + wm * 128 + mf * 16 + l4 * 4 + r;
          int col = n0 + wn * 32 + nfg * 16 + l15;
          float gf = __half2float(__float2half(acc[nfg][mf][r]));      // gate fp16 cast
          float uf = __half2float(__float2half(acc[2 + nfg][mf][r]));  // up fp16 cast
          float sig = 1.f / (1.f + __expf(-gf));
          float sil = __half2float(__float2half(gf * sig));            // silu fp16 cast
          O[(size_t)row * OW + col] = __float2half(sil * uf);          // intermediate fp16
        }
  } else {
    float* O = (float*)OUT;
    #pragma unroll
    for (int nf = 0; nf < 4; ++nf)
      #pragma unroll
      for (int mf = 0; mf < 8; ++mf)
        #pragma unroll
        for (int r = 0; r < 4; ++r) {
          int row = row0 + wm * 128 + mf * 16 + l4 * 4 + r;
          int col = n0 + (nf >> 1) * T1OFF + wn * 32 + (nf & 1) * 16 + l15;
          O[(size_t)row * OW + col] = __half2float(__float2half(acc[nf][mf][r]));
        }
  }
}

// ========== GEMM2 kernel: R13's proven 8-wave tall-narrow (unchanged) ==========
template <int KDIM, int NW, int T1OFF, int OW, bool SILU, int BXS>
__global__ __launch_bounds__(512, 4) void awq_gemm(const __half* __restrict__ A,
                                                   const uint32_t* __restrict__ RP,
                                                   const uint32_t* __restrict__ SMZ,
                                                   void* __restrict__ OUT) {
  constexpr int ABUF = 128 * 64 * 2;
  constexpr int BBUF = 8 * 256 * 4;
  constexpr int BOFF = 3 * ABUF;
  constexpr int ZOFF = BOFF + 3 * BBUF;
  __shared__ __align__(16) unsigned char smem[ZOFF + 2048];  // 75776

  const int tid = threadIdx.x;
  const int l = tid & 63;
  const int wv = tid >> 6;
  const int l15 = l & 15;
  const int l4 = l >> 4;
  const int wc = wv * 16;

  const int row0 = blockIdx.y * 128;
  const int n0 = blockIdx.x * BXS;

  const __half* asrc[2];
  #pragma unroll
  for (int it = 0; it < 2; ++it) {
    int m = it * 64 + (tid >> 3);
    int cs = tid & 7;
    int kc = cs ^ (m & 7);
    asrc[it] = A + (size_t)(row0 + m) * KDIM + kc * 8;
  }

  const uint32_t* bsrc;
  {
    int qr = tid >> 6;
    int c4 = (tid & 63) * 4;
    int S = ((qr & 1) << 4) | ((qr >> 1) << 2);
    int cS = c4 ^ S;
    int bcol = (cS < 128) ? n0 + cS : n0 + T1OFF + (cS - 128);
    bsrc = RP + (size_t)qr * NW + bcol;
  }

  const uint32_t* zsrc;
  {
    int w3 = wv & 3;
    int zc = w3 * 64 + l;
    zsrc = SMZ + ((zc < 128) ? n0 + zc : n0 + T1OFF + (zc - 128));
  }
  const int zdst = ZOFF + (wv & 3) * 256;

  f32x4 acc0[8], acc1[8];
  const f32x4 zero4 = {0.f, 0.f, 0.f, 0.f};
  #pragma unroll
  for (int mf = 0; mf < 8; ++mf) { acc0[mf] = zero4; acc1[mf] = zero4; }

  uint32_t s2[2], z2[2];
  constexpr int NSTEP = KDIM / 64;

  #pragma unroll
  for (int it = 0; it < 2; ++it)
    GLD_LDS16(asrc[it], &smem[it * 8192 + tid * 16]);
  GLD_LDS16(bsrc, &smem[BOFF + tid * 16]);
  GLD_LDS4(zsrc, &smem[zdst]);
  #pragma unroll
  for (int it = 0; it < 2; ++it)
    GLD_LDS16(asrc[it] + 64, &smem[ABUF + it * 8192 + tid * 16]);
  GLD_LDS16(bsrc + (size_t)8 * NW, &smem[BOFF + BBUF + tid * 16]);

  int cur = 0, stg = 2;
  for (int t = 0; t < NSTEP; ++t) {
    if (t == NSTEP - 1)      asm volatile("s_waitcnt vmcnt(0)" ::: "memory");
    else if (t & 1)          asm volatile("s_waitcnt vmcnt(4)" ::: "memory");
    else                     asm volatile("s_waitcnt vmcnt(3)" ::: "memory");
    __builtin_amdgcn_s_barrier();

    if (t + 2 < NSTEP) {
      #pragma unroll
      for (int it = 0; it < 2; ++it)
        GLD_LDS16(asrc[it] + (size_t)(t + 2) * 64,
                  &smem[stg * ABUF + it * 8192 + tid * 16]);
      GLD_LDS16(bsrc + (size_t)(t + 2) * 8 * NW, &smem[BOFF + stg * BBUF + tid * 16]);
      if (((t + 2) & 1) == 0) {
        const int g = (t + 2) >> 1;
        GLD_LDS4(zsrc + (size_t)g * NW, &smem[zdst + (g & 1) * 1024]);
      }
    }

    if ((t & 1) == 0) {
      const uint32_t* zl = (const uint32_t*)&smem[ZOFF + ((t >> 1) & 1) * 1024];
      uint32_t u0 = zl[wc + l15];
      uint32_t u1 = zl[128 + wc + l15];
      uint32_t lo0 = u0 & 0xFFFFu, lo1 = u1 & 0xFFFFu;
      s2[0] = lo0 | (lo0 << 16);
      z2[0] = (u0 & 0xFFFF0000u) | (u0 >> 16);
      s2[1] = lo1 | (lo1 << 16);
      z2[1] = (u1 & 0xFFFF0000u) | (u1 >> 16);
    }

    uint32_t bq[2][2];
    const uint32_t* bdw = (const uint32_t*)&smem[BOFF + cur * BBUF];
    #pragma unroll
    for (int kk = 0; kk < 2; ++kk) {
      const int Sl = ((l4 & 1) << 4) | (kk << 3) | ((l4 >> 1) << 2);
      const int qrow = (kk * 4 + l4) * 256;
      bq[kk][0] = bdw[qrow + ((wc + l15) ^ Sl)];
      bq[kk][1] = bdw[qrow + ((128 + wc + l15) ^ Sl)];
    }

    const unsigned char* abase = &smem[cur * ABUF];
    __builtin_amdgcn_s_setprio(1);
    #pragma unroll
    for (int kk = 0; kk < 2; ++kk) {
      half8 b0 = dequant8(bq[kk][0], bith2(s2[0]), bith2(z2[0]));
      half8 b1 = dequant8(bq[kk][1], bith2(s2[1]), bith2(z2[1]));
      const int chunkoff = ((kk * 4 + l4) ^ (l15 & 7)) * 16;
      #pragma unroll
      for (int mf = 0; mf < 8; ++mf) {
        half8 a = *(const half8*)(abase + (mf * 16 + l15) * 128 + chunkoff);
        acc0[mf] = __builtin_amdgcn_mfma_f32_16x16x32_f16(a, b0, acc0[mf], 0, 0, 0);
        acc1[mf] = __builtin_amdgcn_mfma_f32_16x16x32_f16(a, b1, acc1[mf], 0, 0, 0);
      }
    }
    __builtin_amdgcn_s_setprio(0);

    cur = (cur == 2) ? 0 : cur + 1;
    stg = (stg == 2) ? 0 : stg + 1;
  }

  if (SILU) {
    __half* O = (__half*)OUT;
    #pragma unroll
    for (int mf = 0; mf < 8; ++mf)
      #pragma unroll
      for (int r = 0; r < 4; ++r) {
        int row = row0 + mf * 16 + l4 * 4 + r;
        int col = n0 + wc + l15;
        float gf = __half2float(__float2half(acc0[mf][r]));
        float uf = __half2float(__float2half(acc1[mf][r]));
        float sig = 1.f / (1.f + __expf(-gf));
        float sil = __half2float(__float2half(gf * sig));
        O[(size_t)row * OW + col] = __float2half(sil * uf);
      }
  } else {
    float* O = (float*)OUT;
    #pragma unroll
    for (int mf = 0; mf < 8; ++mf)
      #pragma unroll
      for (int r = 0; r < 4; ++r) {
        int row = row0 + mf * 16 + l4 * 4 + r;
        int col0 = n0 + wc + l15;
        int col1 = n0 + T1OFF + wc + l15;
        O[(size_t)row * OW + col0] = __half2float(__float2half(acc0[mf][r]));
        O[(size_t)row * OW + col1] = __half2float(__float2half(acc1[mf][r]));
      }
  }
}

// ---------- launch ----------
// Workspace phase-aliasing (stay under round-1-proven-safe 263,397,376 B):
//   phase 1 (through GEMM1): interm | rp_gu | smz_gu | xh   = 256,688,128 B
//   phase 2 (after GEMM1):   interm | rp_dn | smz_dn        = 191,258,624 B
extern "C" void kernel_launch(void* const* d_in, const int* in_sizes, int n_in,
                              void* d_out, int out_size, void* d_ws, size_t ws_size,
                              hipStream_t stream) {
  const float* x_f32 = (const float*)d_in[0];          // harness upcasts fp16 -> fp32
  const int* qw_gu = (const int*)d_in[1];
  const int* qz_gu = (const int*)d_in[2];
  const float* sc_gu = (const float*)d_in[3];          // fp32 (upcast)
  const int* qw_dn = (const int*)d_in[4];
  const int* qz_dn = (const int*)d_in[5];
  const float* sc_dn = (const float*)d_in[6];          // fp32 (upcast)

  char* ws = (char*)d_ws;
  __half* interm   = (__half*)ws;                      // 155,189,248
  uint32_t* rp_gu  = (uint32_t*)(ws + 155189248ull);   // 67,895,296
  uint32_t* smz_gu = (uint32_t*)(ws + 223084544ull);   // 4,243,456
  __half* xh       = (__half*)(ws + 227328000ull);     // 29,360,128
  uint32_t* rp_dn  = (uint32_t*)(ws + 155189248ull);   // aliases rp_gu
  uint32_t* smz_dn = (uint32_t*)(ws + 189136896ull);

  // ---- phase 1: prep + GEMM1 ----
  xcvt_kernel<<<14336, 256, 0, stream>>>(x_f32, xh);
  repack_kernel<<<dim3(148, 112), 256, 0, stream>>>(qw_gu, rp_gu, 4736);
  smz_kernel<<<dim3(148, 28), 256, 0, stream>>>(sc_gu, qz_gu, smz_gu, 4736);

  // GEMM1: 256x256 tile (128 gate + 128 up), single-barrier counted-vmcnt
  awq_gemm_big<3584, 37888, 18944, 18944, true, 128>
      <<<dim3(148, 16), 512, 0, stream>>>(xh, rp_gu, smz_gu, (void*)interm);

  // ---- phase 2: prep + GEMM2 (aliased scratch) ----
  repack_kernel<<<dim3(14, 592), 256, 0, stream>>>(qw_dn, rp_dn, 448);
  smz_kernel<<<dim3(14, 148), 256, 0, stream>>>(sc_dn, qz_dn, smz_dn, 448);

  // GEMM2: R13's proven 128x256 instance
  awq_gemm<18944, 3584, 128, 3584, false, 256>
      <<<dim3(14, 32), 512, 0, stream>>>(interm, rp_dn, smz_dn, d_out);
}